// Round 12
// baseline (235.948 us; speedup 1.0000x reference)
//
#include <hip/hip_runtime.h>

#define CIN   256
#define OC    256
#define K_TOT 2304             // 256*9
#define CCH   32               // channels per K-chunk
#define NCHK  8                // K chunks
#define KCH   288              // k-values per chunk (tap-major: k = tap*32 + c)
#define SSTR  296              // LDS row stride (bf16 elems), 16B-aligned, padded
#define DM    64               // px per block, M-tile

#define N_DW  (OC * K_TOT)     // deform weight elements (589824)
#define N_OW  (32 * K_TOT)     // padded offset weight elements (73728)
#define N_CVT (2 * N_DW + 2 * N_OW)          // 1327104
#define CVT_BLOCKS (N_CVT / 4 / 512)         // 648 (512-thread blocks)
#define XT_K_ELEMS ((size_t)16 * 256 * 256)      // 1048576
#define XT_S_ELEMS ((size_t)16 * 1024 * 256)     // 4194304

typedef short  bf16x8 __attribute__((ext_vector_type(8)));
typedef float  f32x4  __attribute__((ext_vector_type(4)));
typedef short  sh4    __attribute__((ext_vector_type(4)));
typedef _Float16 h4   __attribute__((ext_vector_type(4)));
typedef unsigned short ushort_t;

__device__ __forceinline__ ushort_t f2bf(float f) {
    unsigned u = __builtin_bit_cast(unsigned, f);
    u += 0x7fffu + ((u >> 16) & 1u);          // RNE
    return (ushort_t)(u >> 16);
}
__device__ __forceinline__ float bf2f(short s) {
    return __builtin_bit_cast(float, ((unsigned)(unsigned short)s) << 16);
}

// ---------------------------------------------------------------------------
// prep kernel (r10 structure, verified): (a) weight fp32->bf16 cvt with
// tap-major K permutation; (b) input transpose NCHW fp32 -> HWC bf16, 512
// threads (8 waves). Also zeroes the 256-elem ZERO ROW after xt_s (OOB taps).
// ---------------------------------------------------------------------------
__global__ __launch_bounds__(512) void prep_k(
    const float* __restrict__ tdw, const float* __restrict__ sdw,
    const float* __restrict__ tow, const float* __restrict__ sow,
    const float* __restrict__ kin, const float* __restrict__ sin_,
    ushort_t* __restrict__ wk_d, ushort_t* __restrict__ ws_d,
    ushort_t* __restrict__ wk_o, ushort_t* __restrict__ ws_o,
    ushort_t* __restrict__ xt_k, ushort_t* __restrict__ xt_s)
{
    __shared__ ushort_t tile[64][264];    // transpose staging

    if (blockIdx.x == 0 && threadIdx.x < 64) {   // zero row for OOB taps
        ushort4 z = {0, 0, 0, 0};
        *(ushort4*)&xt_s[XT_S_ELEMS + (size_t)threadIdx.x * 4] = z;
    }

    if (blockIdx.x < CVT_BLOCKS) {
        const int i = (blockIdx.x * 512 + threadIdx.x) * 4;
        const float* src; ushort_t* dst; int j; bool offw = false;
        if (i < N_DW)                    { src = tdw; dst = wk_d; j = i; }
        else if (i < 2 * N_DW)           { src = sdw; dst = ws_d; j = i - N_DW; }
        else if (i < 2 * N_DW + N_OW)    { src = tow; dst = wk_o; j = i - 2 * N_DW; offw = true; }
        else                             { src = sow; dst = ws_o; j = i - 2 * N_DW - N_OW; offw = true; }
        const int oc = j / K_TOT;
        const int k  = j - oc * K_TOT;
        const int cc = k / KCH;
        const int r  = k - cc * KCH;     // r%4==0, so cl..cl+3 share one tap
        const int tap = r >> 5;
        const int cl  = r & 31;
        ushort4 o4 = {0, 0, 0, 0};
        if (!offw || oc < 18) {
            const float* sp = &src[((size_t)oc * CIN + cc * 32 + cl) * 9 + tap];
            o4.x = f2bf(sp[0]); o4.y = f2bf(sp[9]); o4.z = f2bf(sp[18]); o4.w = f2bf(sp[27]);
        }
        *(ushort4*)&dst[j] = o4;
        return;
    }

    // ---- transpose branch (512 thr = 8 waves) -----------------------------
    const int bx2 = blockIdx.x - CVT_BLOCKS;     // 0..319
    int H, W, b, px0; const float* x; ushort_t* xt;
    if (bx2 < 64) {                       // kernel: 16 b * 4 tiles
        H = 16; W = 16; x = kin; xt = xt_k;
        b = bx2 >> 2; px0 = (bx2 & 3) * 64;
    } else {                              // search: 16 b * 16 tiles
        int t2 = bx2 - 64;
        H = 32; W = 32; x = sin_; xt = xt_s;
        b = t2 >> 4; px0 = (t2 & 15) * 64;
    }
    const int HW = H * W;
    const int t = threadIdx.x, lane = t & 63, wv = t >> 6;   // wv: 0..7
    const float* xb = x + (size_t)b * CIN * HW;

    for (int it = 0; it < 8; ++it) {
        const int ch = wv * 32 + it * 4 + (lane >> 4);
        const int pq = (lane & 15) * 4;
        float4 v = *(const float4*)&xb[(size_t)ch * HW + px0 + pq];
        tile[pq + 0][ch] = f2bf(v.x);
        tile[pq + 1][ch] = f2bf(v.y);
        tile[pq + 2][ch] = f2bf(v.z);
        tile[pq + 3][ch] = f2bf(v.w);
    }
    __syncthreads();
    for (int it = 0; it < 4; ++it) {
        const int px = it * 16 + wv * 2 + (lane >> 5);
        const int cg = (lane & 31) * 8;
        bf16x8 v = *(const bf16x8*)&tile[px][cg];
        *(bf16x8*)&xt[((size_t)b * HW + px0 + px) * 256 + cg] = v;
    }
}

// ---------------------------------------------------------------------------
// FUSED offset-conv + deformable-conv kernel. 320 blocks x 512 thr, same
// (b, px0) tile mapping + XCD-bijective swizzle as rounds 5-11.
//
// Round-12: LDS DIET -> 3 blocks/CU (occupancy 19.4% -> ~28%). The deform
// phase is outstanding-miss (Little's-law) bound and the per-wave in-flight
// depth is register-capped at 2 (r1/r4/r6 spill wall), so the remaining
// axis for more outstanding misses is MORE WAVES.
//  * conv reduce: 3-stage TREE (waves 4-7 -> 0-3 -> 0-1 -> 0), peak staging
//    36.9 KB, reusing the smp union region (was a flat 63 KB sred).
//  * params compacted: sidx int->short (idx < 1024), swt f32->_Float16
//    (bilinear wts in [0,1]; fp16 rel-err 5e-4 << 0.03125 tolerance).
//  * union = smp 37.9K | sidxS 4.6K | swtH 4.6K = 46K; + offsL 4.6K
//    => 50.5 KB per block => 3 blocks/CU. launch_bounds(512,6): VGPR cap
//    ~84 (current use 64 -> depth-2 pipeline untouched).
// Phase A: offset conv (r9 structure, unconditional zero-row A-loads).
// Phase B: bilinear params from offsL (LDS, no global round-trip).
// Phase C: deform GEMM, exact r5 loop (depth-2 gather, rolling bq, raw
//   lgkm-only barriers, setprio).
// Canaries: WRITE_SIZE ~21.9 MB (spill), VGPR <= 84, Occupancy ~28%.
// ---------------------------------------------------------------------------
__device__ __forceinline__ void dcn_load4(
    bf16x8* c, const ushort_t* __restrict__ xtb, int4 id, int cb)
{
    c[0] = *(const bf16x8*)&xtb[(size_t)id.x * 256 + cb];
    c[1] = *(const bf16x8*)&xtb[(size_t)id.y * 256 + cb];
    c[2] = *(const bf16x8*)&xtb[(size_t)id.z * 256 + cb];
    c[3] = *(const bf16x8*)&xtb[(size_t)id.w * 256 + cb];
}
__device__ __forceinline__ void dcn_proc2(
    ushort_t* swb, int so, const bf16x8* c, float4 wt)
{
    bf16x8 r;
#pragma unroll
    for (int j = 0; j < 8; ++j) {
        const float v = wt.x * bf2f(c[0][j]) + wt.y * bf2f(c[1][j])
                      + wt.z * bf2f(c[2][j]) + wt.w * bf2f(c[3][j]);
        r[j] = (short)f2bf(v);
    }
    *(bf16x8*)&swb[so] = r;
}

__global__ __launch_bounds__(512, 6) void deform_gemm_k(
    const ushort_t* __restrict__ xt_k,
    const ushort_t* __restrict__ kwo, const float* __restrict__ kbias,
    float* __restrict__ koff, const ushort_t* __restrict__ kwd,
    float* __restrict__ kout,
    const ushort_t* __restrict__ xt_s,
    const ushort_t* __restrict__ swo, const float* __restrict__ sbias,
    float* __restrict__ soff, const ushort_t* __restrict__ swd,
    float* __restrict__ sout)
{
    // union (47104 B):
    //   phase A: red[4][64][36] f32 tree-staging (36864 B)
    //   phase B/C: smp[64][SSTR] u16 (37888) + sidxS[64][9][4] i16
    //              (4608, @37888) + swtH[64][9][4] f16 (4608, @42496)
    __shared__ __align__(16) char  uni[47104];
    __shared__ __align__(16) float offsL[18][64];       // 4608 B
    // total 51712 B -> 3 blocks/CU

    float    (*red)[64][36] = (float(*)[64][36])uni;
    ushort_t (*smp)[SSTR]   = (ushort_t(*)[SSTR])uni;
    short    (*sidxS)[9][4] = (short(*)[9][4])(uni + 37888);
    _Float16 (*swtH)[9][4]  = (_Float16(*)[9][4])(uni + 42496);

    int H, W, sh, b, px0; int zrel;
    const ushort_t *xt, *wgo, *wgd; const float* bias; float *ooff, *out;
    if (blockIdx.x < 64) {                // kernel: 16 b * 4 tiles
        const int xcd = blockIdx.x & 7, i = blockIdx.x >> 3;   // i: 0..7
        H = 16; W = 16; sh = 4; xt = xt_k; wgo = kwo; bias = kbias;
        ooff = koff; wgd = kwd; out = kout;
        b = xcd + 8 * (i & 1); px0 = (i >> 1) * 64;
        zrel = (int)(XT_K_ELEMS + XT_S_ELEMS - (size_t)b * 256 * 256);
    } else {                              // search: 16 b * 16 tiles
        const int t2 = blockIdx.x - 64;                        // 0..255
        const int xcd = t2 & 7, i = t2 >> 3;                   // i: 0..31
        H = 32; W = 32; sh = 5; xt = xt_s; wgo = swo; bias = sbias;
        ooff = soff; wgd = swd; out = sout;
        b = xcd + 8 * (i & 1); px0 = (i >> 1) * 64;
        zrel = (int)(XT_S_ELEMS - (size_t)b * 1024 * 256);
    }
    const int HW = H * W;
    const int t = threadIdx.x, lane = t & 63, wv = t >> 6;
    const int l15 = lane & 15;
    const int cg8 = (lane >> 4) * 8;
    const ushort_t* xtb = xt + (size_t)b * HW * 256;

    // ===================== phase A: offset conv ============================
    {
        const int kh = wv;                // wave = one K-chunk
        int h[4], wc[4];
#pragma unroll
        for (int mt = 0; mt < 4; ++mt) {
            const int px = px0 + mt * 16 + l15;
            h[mt]  = px >> sh;
            wc[mt] = px & (W - 1);
        }
        const ushort_t* wrow0 = wgo + (size_t)(l15)      * K_TOT + cg8;
        const ushort_t* wrow1 = wgo + (size_t)(16 + l15) * K_TOT + cg8;
        const int cb = kh * 32 + cg8;
        const size_t kg0 = (size_t)kh * KCH;

        f32x4 acc[4][2] = {};
#pragma unroll
        for (int ks = 0; ks < 9; ++ks) {
            const bf16x8 b0 = *(const bf16x8*)&wrow0[kg0 + (size_t)ks * 32];
            const bf16x8 b1 = *(const bf16x8*)&wrow1[kg0 + (size_t)ks * 32];
            const int dy = ks / 3 - 1, dx = ks % 3 - 1;
            bf16x8 a[4];
#pragma unroll
            for (int mt = 0; mt < 4; ++mt) {
                const int y  = h[mt] + dy;
                const int xx = wc[mt] + dx;
                const bool ok = ((unsigned)y < (unsigned)H) && ((unsigned)xx < (unsigned)W);
                const int off = ok ? (((y << sh) + xx) * 256 + cb) : (zrel + cb);
                a[mt] = *(const bf16x8*)&xtb[off];      // unconditional
            }
#pragma unroll
            for (int mt = 0; mt < 4; ++mt) {
                acc[mt][0] = __builtin_amdgcn_mfma_f32_16x16x32_bf16(a[mt], b0, acc[mt][0], 0, 0, 0);
                acc[mt][1] = __builtin_amdgcn_mfma_f32_16x16x32_bf16(a[mt], b1, acc[mt][1], 0, 0, 0);
            }
        }

        // ---- 3-stage tree reduce (peak staging 36.9 KB in union) ----------
        // stage 1: waves 4-7 -> waves 0-3
        if (kh >= 4) {
#pragma unroll
            for (int mt = 0; mt < 4; ++mt)
#pragma unroll
                for (int nt = 0; nt < 2; ++nt)
                    *(float4*)&red[kh - 4][lane][(mt * 2 + nt) * 4] = *(float4*)&acc[mt][nt];
        }
        __syncthreads();
        if (kh < 4) {
#pragma unroll
            for (int mt = 0; mt < 4; ++mt)
#pragma unroll
                for (int nt = 0; nt < 2; ++nt) {
                    const float4 o = *(const float4*)&red[kh][lane][(mt * 2 + nt) * 4];
                    acc[mt][nt].x += o.x; acc[mt][nt].y += o.y;
                    acc[mt][nt].z += o.z; acc[mt][nt].w += o.w;
                }
        }
        __syncthreads();
        // stage 2: waves 2,3 -> waves 0,1
        if (kh == 2 || kh == 3) {
#pragma unroll
            for (int mt = 0; mt < 4; ++mt)
#pragma unroll
                for (int nt = 0; nt < 2; ++nt)
                    *(float4*)&red[kh - 2][lane][(mt * 2 + nt) * 4] = *(float4*)&acc[mt][nt];
        }
        __syncthreads();
        if (kh < 2) {
#pragma unroll
            for (int mt = 0; mt < 4; ++mt)
#pragma unroll
                for (int nt = 0; nt < 2; ++nt) {
                    const float4 o = *(const float4*)&red[kh][lane][(mt * 2 + nt) * 4];
                    acc[mt][nt].x += o.x; acc[mt][nt].y += o.y;
                    acc[mt][nt].z += o.z; acc[mt][nt].w += o.w;
                }
        }
        __syncthreads();
        // stage 3: wave 1 -> wave 0
        if (kh == 1) {
#pragma unroll
            for (int mt = 0; mt < 4; ++mt)
#pragma unroll
                for (int nt = 0; nt < 2; ++nt)
                    *(float4*)&red[0][lane][(mt * 2 + nt) * 4] = *(float4*)&acc[mt][nt];
        }
        __syncthreads();
        if (kh == 0) {
            const int prow = (lane >> 4) * 4;
#pragma unroll
            for (int nt = 0; nt < 2; ++nt) {
                const int oc = nt * 16 + l15;
                if (oc < 18) {
                    const float bs = bias[oc];
#pragma unroll
                    for (int mt = 0; mt < 4; ++mt) {
                        float4 r = *(float4*)&acc[mt][nt];
                        const float4 o = *(const float4*)&red[0][lane][(mt * 2 + nt) * 4];
                        r.x += o.x + bs; r.y += o.y + bs;
                        r.z += o.z + bs; r.w += o.w + bs;
                        *(float4*)(ooff + ((size_t)b * 18 + oc) * HW + px0 + mt * 16 + prow) = r;
                        *(float4*)&offsL[oc][mt * 16 + prow] = r;
                    }
                }
            }
        }
        __syncthreads();     // offsL visible; red region dead
    }

    // ===================== phase B: bilinear params ========================
#pragma unroll
    for (int u = 0; u < 2; ++u) {
        const int s = t + u * 512;
        if (s < DM * 9) {
            const int p = s / 9, k = s - 9 * p;
            const int pix = px0 + p;
            const int hh = pix >> sh;
            const int ww = pix & (W - 1);
            const float dy = offsL[2 * k    ][p];
            const float dx = offsL[2 * k + 1][p];
            const float sy = (float)(hh + k / 3 - 1) + dy;
            const float sx = (float)(ww + k % 3 - 1) + dx;
            const float y0f = floorf(sy), x0f = floorf(sx);
            const float ly = sy - y0f, lx = sx - x0f;
            const int y0 = (int)y0f, x0 = (int)x0f;
#pragma unroll
            for (int j = 0; j < 4; ++j) {
                const int yy = y0 + (j >> 1);
                const int xx = x0 + (j & 1);
                const bool ok = ((unsigned)yy < (unsigned)H) && ((unsigned)xx < (unsigned)W);
                sidxS[p][k][j] = (short)(min(max(yy, 0), H - 1) * W + min(max(xx, 0), W - 1));
                const float wj = ((j >> 1) ? ly : 1.f - ly) * ((j & 1) ? lx : 1.f - lx);
                swtH[p][k][j] = (_Float16)(ok ? wj : 0.f);
            }
        }
    }
    __syncthreads();

    // ===================== phase C: deform GEMM (r5 loop) ==================
    const int ocb = wv * 32;
    const bool live4 = (t < 256);         // 2304 - 4*512 = 256 fifth-units

    const int g0  = t >> 2;
    const int cgE = (t & 3) * 8;
    int uso[5];
#pragma unroll
    for (int q = 0; q < 5; ++q) {
        const int g  = g0 + q * 128;
        const int px = g / 9, tap = g - 9 * px;
        uso[q] = px * SSTR + tap * 32 + (t & 3) * 8;
    }

    const ushort_t* wrow0 = wgd + (size_t)(ocb      + l15) * K_TOT + cg8;
    const ushort_t* wrow1 = wgd + (size_t)(ocb + 16 + l15) * K_TOT + cg8;
    ushort_t* smpb = &smp[0][0];
    const sh4* sidxF = (const sh4*)(uni + 37888);
    const h4*  swtF  = (const h4*) (uni + 42496);

    f32x4 acc[4][2] = {};

    for (int cc = 0; cc < NCHK; ++cc) {
        const int cb = cc * 32 + cgE;
        const size_t kg0 = (size_t)cc * KCH;

        // ---- gather phase: depth-2 rolling pipeline (cA/cB slots) ---------
        bf16x8 cA[4], cB[4];
        float4 wA, wB;
        bf16x8 bq[2][2];
        {
            const sh4 iv = sidxF[g0]; const h4 wvv = swtF[g0];
            const int4 id = {iv.x, iv.y, iv.z, iv.w};
            wA = (float4){(float)wvv.x, (float)wvv.y, (float)wvv.z, (float)wvv.w};
            dcn_load4(cA, xtb, id, cb);
        }
        {
            const sh4 iv = sidxF[g0 + 128]; const h4 wvv = swtF[g0 + 128];
            const int4 id = {iv.x, iv.y, iv.z, iv.w};
            wB = (float4){(float)wvv.x, (float)wvv.y, (float)wvv.z, (float)wvv.w};
            dcn_load4(cB, xtb, id, cb);
        }
        bq[0][0] = *(const bf16x8*)&wrow0[kg0];
        bq[0][1] = *(const bf16x8*)&wrow1[kg0];

        dcn_proc2(smpb, uso[0], cA, wA);
        {
            const sh4 iv = sidxF[g0 + 256]; const h4 wvv = swtF[g0 + 256];
            const int4 id = {iv.x, iv.y, iv.z, iv.w};
            wA = (float4){(float)wvv.x, (float)wvv.y, (float)wvv.z, (float)wvv.w};
            dcn_load4(cA, xtb, id, cb);
        }
        dcn_proc2(smpb, uso[1], cB, wB);
        {
            const sh4 iv = sidxF[g0 + 384]; const h4 wvv = swtF[g0 + 384];
            const int4 id = {iv.x, iv.y, iv.z, iv.w};
            wB = (float4){(float)wvv.x, (float)wvv.y, (float)wvv.z, (float)wvv.w};
            dcn_load4(cB, xtb, id, cb);
        }
        dcn_proc2(smpb, uso[2], cA, wA);
        if (live4) {
            const sh4 iv = sidxF[g0 + 512]; const h4 wvv = swtF[g0 + 512];
            const int4 id = {iv.x, iv.y, iv.z, iv.w};
            wA = (float4){(float)wvv.x, (float)wvv.y, (float)wvv.z, (float)wvv.w};
            dcn_load4(cA, xtb, id, cb);
        }
        dcn_proc2(smpb, uso[3], cB, wB);
        if (live4) dcn_proc2(smpb, uso[4], cA, wA);

        // ---- barrier A: smp writes visible (lgkm only, vmem in flight) ----
        asm volatile("s_waitcnt lgkmcnt(0)" ::: "memory");
        __builtin_amdgcn_sched_barrier(0);
        __builtin_amdgcn_s_barrier();
        __builtin_amdgcn_sched_barrier(0);

        // ---- MFMA phase: rolling 2-deep B register buffer -----------------
        __builtin_amdgcn_s_setprio(1);
#pragma unroll
        for (int ks = 0; ks < 9; ++ks) {
            if (ks < 8) {
                bq[(ks + 1) & 1][0] = *(const bf16x8*)&wrow0[kg0 + (size_t)(ks + 1) * 32];
                bq[(ks + 1) & 1][1] = *(const bf16x8*)&wrow1[kg0 + (size_t)(ks + 1) * 32];
            }
            bf16x8 a[4];
#pragma unroll
            for (int mt = 0; mt < 4; ++mt)
                a[mt] = *(const bf16x8*)&smp[mt * 16 + l15][ks * 32 + cg8];
#pragma unroll
            for (int mt = 0; mt < 4; ++mt) {
                acc[mt][0] = __builtin_amdgcn_mfma_f32_16x16x32_bf16(a[mt], bq[ks & 1][0], acc[mt][0], 0, 0, 0);
                acc[mt][1] = __builtin_amdgcn_mfma_f32_16x16x32_bf16(a[mt], bq[ks & 1][1], acc[mt][1], 0, 0, 0);
            }
        }
        __builtin_amdgcn_s_setprio(0);

        // ---- barrier B: all smp reads consumed before next chunk's writes -
        if (cc < NCHK - 1) {
            __builtin_amdgcn_sched_barrier(0);
            __builtin_amdgcn_s_barrier();
            __builtin_amdgcn_sched_barrier(0);
        }
    }

    // ---- epilogue ---------------------------------------------------------
    const int prow = (lane >> 4) * 4;
#pragma unroll
    for (int mt = 0; mt < 4; ++mt) {
#pragma unroll
        for (int nt = 0; nt < 2; ++nt) {
            const int oc = ocb + nt * 16 + l15;
            float* op = out + ((size_t)b * OC + oc) * HW + px0 + mt * 16 + prow;
            *(float4*)op = *(float4*)&acc[mt][nt];
        }
    }
}

// ---------------------------------------------------------------------------
// Launcher. Inputs: kernel, search, Toffset_w, Toffset_b, Tdeform_w,
//                   Soffset_w, Soffset_b, Sdeform_w
// Outputs: kernel_out[16,256,16,16], search_out[16,256,32,32],
//          kernel_offset[16,18,16,16], search_offset[16,18,32,32]
// d_ws: 13.15 MB (bf16 weights 2.66 MB + HWC inputs 10.49 MB + 512 B zero
// row appended after xt_s for OOB taps).
// ---------------------------------------------------------------------------
extern "C" void kernel_launch(void* const* d_in, const int* in_sizes, int n_in,
                              void* d_out, int out_size, void* d_ws, size_t ws_size,
                              hipStream_t stream) {
    const float* kin = (const float*)d_in[0];
    const float* sin_ = (const float*)d_in[1];
    const float* tow = (const float*)d_in[2];
    const float* tob = (const float*)d_in[3];
    const float* tdw = (const float*)d_in[4];
    const float* sow = (const float*)d_in[5];
    const float* sob = (const float*)d_in[6];
    const float* sdw = (const float*)d_in[7];

    float* out = (float*)d_out;
    float* out_k  = out;                                      // 16*256*16*16
    float* out_s  = out_k + (size_t)16 * 256 * 16 * 16;       // 16*256*32*32
    float* out_ko = out_s + (size_t)16 * 256 * 32 * 32;       // 16*18*16*16
    float* out_so = out_ko + (size_t)16 * 18 * 16 * 16;       // 16*18*32*32

    ushort_t* wk_d = (ushort_t*)d_ws;                 // [256][2304] tap-major
    ushort_t* ws_d = wk_d + N_DW;
    ushort_t* wk_o = ws_d + N_DW;                     // [32][2304] tap-major
    ushort_t* ws_o = wk_o + N_OW;
    ushort_t* xt_k = ws_o + N_OW;                     // [16][256][256] HWC bf16
    ushort_t* xt_s = xt_k + XT_K_ELEMS;               // [16][1024][256]
    // zero row (256 elems) lives at xt_s + XT_S_ELEMS; prep_k writes it.

    prep_k<<<dim3(CVT_BLOCKS + 320), 512, 0, stream>>>(
        tdw, sdw, tow, sow, kin, sin_,
        wk_d, ws_d, wk_o, ws_o, xt_k, xt_s);

    deform_gemm_k<<<dim3(320), 512, 0, stream>>>(
        xt_k, wk_o, tob, out_ko, wk_d, out_k,
        xt_s, ws_o, sob, out_so, ws_d, out_s);
}

// Round 14
// 202.480 us; speedup vs baseline: 1.1653x; 1.1653x over previous
//
#include <hip/hip_runtime.h>

#define CIN   256
#define OC    256
#define K_TOT 2304             // 256*9
#define CCH   32               // channels per K-chunk
#define NCHK  8                // K chunks
#define KCH   288              // k-values per chunk (tap-major: k = tap*32 + c)
#define SSTR  296              // LDS row stride (bf16 elems), 16B-aligned, padded
#define DM    64               // px per block, M-tile

#define N_DW  (OC * K_TOT)     // deform weight elements (589824)
#define N_OW  (32 * K_TOT)     // padded offset weight elements (73728)
#define N_CVT (2 * N_DW + 2 * N_OW)          // 1327104
#define CVT_BLOCKS (N_CVT / 4 / 512)         // 648 (512-thread blocks)
#define XT_K_ELEMS ((size_t)16 * 256 * 256)      // 1048576
#define XT_S_ELEMS ((size_t)16 * 1024 * 256)     // 4194304

typedef short  bf16x8 __attribute__((ext_vector_type(8)));
typedef float  f32x4  __attribute__((ext_vector_type(4)));
typedef short  sh4    __attribute__((ext_vector_type(4)));
typedef _Float16 h4   __attribute__((ext_vector_type(4)));
typedef unsigned short ushort_t;

__device__ __forceinline__ ushort_t f2bf(float f) {
    unsigned u = __builtin_bit_cast(unsigned, f);
    u += 0x7fffu + ((u >> 16) & 1u);          // RNE
    return (ushort_t)(u >> 16);
}
__device__ __forceinline__ float bf2f(short s) {
    return __builtin_bit_cast(float, ((unsigned)(unsigned short)s) << 16);
}

// ---------------------------------------------------------------------------
// prep kernel (r10 structure, verified): (a) weight fp32->bf16 cvt with
// tap-major K permutation; (b) input transpose NCHW fp32 -> HWC bf16, 512
// threads (8 waves). Also zeroes the 256-elem ZERO ROW after xt_s (OOB taps).
// ---------------------------------------------------------------------------
__global__ __launch_bounds__(512) void prep_k(
    const float* __restrict__ tdw, const float* __restrict__ sdw,
    const float* __restrict__ tow, const float* __restrict__ sow,
    const float* __restrict__ kin, const float* __restrict__ sin_,
    ushort_t* __restrict__ wk_d, ushort_t* __restrict__ ws_d,
    ushort_t* __restrict__ wk_o, ushort_t* __restrict__ ws_o,
    ushort_t* __restrict__ xt_k, ushort_t* __restrict__ xt_s)
{
    __shared__ ushort_t tile[64][264];    // transpose staging

    if (blockIdx.x == 0 && threadIdx.x < 64) {   // zero row for OOB taps
        ushort4 z = {0, 0, 0, 0};
        *(ushort4*)&xt_s[XT_S_ELEMS + (size_t)threadIdx.x * 4] = z;
    }

    if (blockIdx.x < CVT_BLOCKS) {
        const int i = (blockIdx.x * 512 + threadIdx.x) * 4;
        const float* src; ushort_t* dst; int j; bool offw = false;
        if (i < N_DW)                    { src = tdw; dst = wk_d; j = i; }
        else if (i < 2 * N_DW)           { src = sdw; dst = ws_d; j = i - N_DW; }
        else if (i < 2 * N_DW + N_OW)    { src = tow; dst = wk_o; j = i - 2 * N_DW; offw = true; }
        else                             { src = sow; dst = ws_o; j = i - 2 * N_DW - N_OW; offw = true; }
        const int oc = j / K_TOT;
        const int k  = j - oc * K_TOT;
        const int cc = k / KCH;
        const int r  = k - cc * KCH;     // r%4==0, so cl..cl+3 share one tap
        const int tap = r >> 5;
        const int cl  = r & 31;
        ushort4 o4 = {0, 0, 0, 0};
        if (!offw || oc < 18) {
            const float* sp = &src[((size_t)oc * CIN + cc * 32 + cl) * 9 + tap];
            o4.x = f2bf(sp[0]); o4.y = f2bf(sp[9]); o4.z = f2bf(sp[18]); o4.w = f2bf(sp[27]);
        }
        *(ushort4*)&dst[j] = o4;
        return;
    }

    // ---- transpose branch (512 thr = 8 waves) -----------------------------
    const int bx2 = blockIdx.x - CVT_BLOCKS;     // 0..319
    int H, W, b, px0; const float* x; ushort_t* xt;
    if (bx2 < 64) {                       // kernel: 16 b * 4 tiles
        H = 16; W = 16; x = kin; xt = xt_k;
        b = bx2 >> 2; px0 = (bx2 & 3) * 64;
    } else {                              // search: 16 b * 16 tiles
        int t2 = bx2 - 64;
        H = 32; W = 32; x = sin_; xt = xt_s;
        b = t2 >> 4; px0 = (t2 & 15) * 64;
    }
    const int HW = H * W;
    const int t = threadIdx.x, lane = t & 63, wv = t >> 6;   // wv: 0..7
    const float* xb = x + (size_t)b * CIN * HW;

    for (int it = 0; it < 8; ++it) {
        const int ch = wv * 32 + it * 4 + (lane >> 4);
        const int pq = (lane & 15) * 4;
        float4 v = *(const float4*)&xb[(size_t)ch * HW + px0 + pq];
        tile[pq + 0][ch] = f2bf(v.x);
        tile[pq + 1][ch] = f2bf(v.y);
        tile[pq + 2][ch] = f2bf(v.z);
        tile[pq + 3][ch] = f2bf(v.w);
    }
    __syncthreads();
    for (int it = 0; it < 4; ++it) {
        const int px = it * 16 + wv * 2 + (lane >> 5);
        const int cg = (lane & 31) * 8;
        bf16x8 v = *(const bf16x8*)&tile[px][cg];
        *(bf16x8*)&xt[((size_t)b * HW + px0 + px) * 256 + cg] = v;
    }
}

// ---------------------------------------------------------------------------
// FUSED offset-conv + deformable-conv kernel. 320 blocks x 512 thr, same
// (b, px0) tile mapping + XCD-bijective swizzle as rounds 5-12.
//
// Round-14 = round-13 resubmitted (r13 bench was an infrastructure failure,
// no hardware signal). One token differs from r12: __launch_bounds__(512,4).
// r12's (512,6) hard-capped VGPR at 84 < the kernel's need -> catastrophic
// spill (VGPR_Count 40, WRITE_SIZE 21.9 -> 109 MB scratch, fused 120 -> 156).
// Occupancy comes from ACTUAL usage + LDS, not the declared bound: r11's
// identical phase-C compiled to 64 VGPR under (512,4), which already
// permits 6 waves/SIMD; the LDS diet (51.7 KB, verified correct in r12)
// is what unlocks the 3rd block/CU.
//  * conv reduce: 3-stage tree, peak staging 36.9 KB in the union.
//  * params: sidx short, swt _Float16 (passed absmax in r12).
//  * union 46K + offsL 4.6K = 51.7 KB -> 3 blocks/CU if VGPR <= 84.
// Canaries: WRITE_SIZE ~21.9 MB (no spill), VGPR 64-84, Occupancy ~28%.
// ---------------------------------------------------------------------------
__device__ __forceinline__ void dcn_load4(
    bf16x8* c, const ushort_t* __restrict__ xtb, int4 id, int cb)
{
    c[0] = *(const bf16x8*)&xtb[(size_t)id.x * 256 + cb];
    c[1] = *(const bf16x8*)&xtb[(size_t)id.y * 256 + cb];
    c[2] = *(const bf16x8*)&xtb[(size_t)id.z * 256 + cb];
    c[3] = *(const bf16x8*)&xtb[(size_t)id.w * 256 + cb];
}
__device__ __forceinline__ void dcn_proc2(
    ushort_t* swb, int so, const bf16x8* c, float4 wt)
{
    bf16x8 r;
#pragma unroll
    for (int j = 0; j < 8; ++j) {
        const float v = wt.x * bf2f(c[0][j]) + wt.y * bf2f(c[1][j])
                      + wt.z * bf2f(c[2][j]) + wt.w * bf2f(c[3][j]);
        r[j] = (short)f2bf(v);
    }
    *(bf16x8*)&swb[so] = r;
}

__global__ __launch_bounds__(512, 4) void deform_gemm_k(
    const ushort_t* __restrict__ xt_k,
    const ushort_t* __restrict__ kwo, const float* __restrict__ kbias,
    float* __restrict__ koff, const ushort_t* __restrict__ kwd,
    float* __restrict__ kout,
    const ushort_t* __restrict__ xt_s,
    const ushort_t* __restrict__ swo, const float* __restrict__ sbias,
    float* __restrict__ soff, const ushort_t* __restrict__ swd,
    float* __restrict__ sout)
{
    // union (47104 B):
    //   phase A: red[4][64][36] f32 tree-staging (36864 B)
    //   phase B/C: smp[64][SSTR] u16 (37888) + sidxS[64][9][4] i16
    //              (4608, @37888) + swtH[64][9][4] f16 (4608, @42496)
    __shared__ __align__(16) char  uni[47104];
    __shared__ __align__(16) float offsL[18][64];       // 4608 B
    // total 51712 B -> 3 blocks/CU (when VGPR <= 84)

    float    (*red)[64][36] = (float(*)[64][36])uni;
    ushort_t (*smp)[SSTR]   = (ushort_t(*)[SSTR])uni;
    short    (*sidxS)[9][4] = (short(*)[9][4])(uni + 37888);
    _Float16 (*swtH)[9][4]  = (_Float16(*)[9][4])(uni + 42496);

    int H, W, sh, b, px0; int zrel;
    const ushort_t *xt, *wgo, *wgd; const float* bias; float *ooff, *out;
    if (blockIdx.x < 64) {                // kernel: 16 b * 4 tiles
        const int xcd = blockIdx.x & 7, i = blockIdx.x >> 3;   // i: 0..7
        H = 16; W = 16; sh = 4; xt = xt_k; wgo = kwo; bias = kbias;
        ooff = koff; wgd = kwd; out = kout;
        b = xcd + 8 * (i & 1); px0 = (i >> 1) * 64;
        zrel = (int)(XT_K_ELEMS + XT_S_ELEMS - (size_t)b * 256 * 256);
    } else {                              // search: 16 b * 16 tiles
        const int t2 = blockIdx.x - 64;                        // 0..255
        const int xcd = t2 & 7, i = t2 >> 3;                   // i: 0..31
        H = 32; W = 32; sh = 5; xt = xt_s; wgo = swo; bias = sbias;
        ooff = soff; wgd = swd; out = sout;
        b = xcd + 8 * (i & 1); px0 = (i >> 1) * 64;
        zrel = (int)(XT_S_ELEMS - (size_t)b * 1024 * 256);
    }
    const int HW = H * W;
    const int t = threadIdx.x, lane = t & 63, wv = t >> 6;
    const int l15 = lane & 15;
    const int cg8 = (lane >> 4) * 8;
    const ushort_t* xtb = xt + (size_t)b * HW * 256;

    // ===================== phase A: offset conv ============================
    {
        const int kh = wv;                // wave = one K-chunk
        int h[4], wc[4];
#pragma unroll
        for (int mt = 0; mt < 4; ++mt) {
            const int px = px0 + mt * 16 + l15;
            h[mt]  = px >> sh;
            wc[mt] = px & (W - 1);
        }
        const ushort_t* wrow0 = wgo + (size_t)(l15)      * K_TOT + cg8;
        const ushort_t* wrow1 = wgo + (size_t)(16 + l15) * K_TOT + cg8;
        const int cb = kh * 32 + cg8;
        const size_t kg0 = (size_t)kh * KCH;

        f32x4 acc[4][2] = {};
#pragma unroll
        for (int ks = 0; ks < 9; ++ks) {
            const bf16x8 b0 = *(const bf16x8*)&wrow0[kg0 + (size_t)ks * 32];
            const bf16x8 b1 = *(const bf16x8*)&wrow1[kg0 + (size_t)ks * 32];
            const int dy = ks / 3 - 1, dx = ks % 3 - 1;
            bf16x8 a[4];
#pragma unroll
            for (int mt = 0; mt < 4; ++mt) {
                const int y  = h[mt] + dy;
                const int xx = wc[mt] + dx;
                const bool ok = ((unsigned)y < (unsigned)H) && ((unsigned)xx < (unsigned)W);
                const int off = ok ? (((y << sh) + xx) * 256 + cb) : (zrel + cb);
                a[mt] = *(const bf16x8*)&xtb[off];      // unconditional
            }
#pragma unroll
            for (int mt = 0; mt < 4; ++mt) {
                acc[mt][0] = __builtin_amdgcn_mfma_f32_16x16x32_bf16(a[mt], b0, acc[mt][0], 0, 0, 0);
                acc[mt][1] = __builtin_amdgcn_mfma_f32_16x16x32_bf16(a[mt], b1, acc[mt][1], 0, 0, 0);
            }
        }

        // ---- 3-stage tree reduce (peak staging 36.9 KB in union) ----------
        if (kh >= 4) {
#pragma unroll
            for (int mt = 0; mt < 4; ++mt)
#pragma unroll
                for (int nt = 0; nt < 2; ++nt)
                    *(float4*)&red[kh - 4][lane][(mt * 2 + nt) * 4] = *(float4*)&acc[mt][nt];
        }
        __syncthreads();
        if (kh < 4) {
#pragma unroll
            for (int mt = 0; mt < 4; ++mt)
#pragma unroll
                for (int nt = 0; nt < 2; ++nt) {
                    const float4 o = *(const float4*)&red[kh][lane][(mt * 2 + nt) * 4];
                    acc[mt][nt].x += o.x; acc[mt][nt].y += o.y;
                    acc[mt][nt].z += o.z; acc[mt][nt].w += o.w;
                }
        }
        __syncthreads();
        if (kh == 2 || kh == 3) {
#pragma unroll
            for (int mt = 0; mt < 4; ++mt)
#pragma unroll
                for (int nt = 0; nt < 2; ++nt)
                    *(float4*)&red[kh - 2][lane][(mt * 2 + nt) * 4] = *(float4*)&acc[mt][nt];
        }
        __syncthreads();
        if (kh < 2) {
#pragma unroll
            for (int mt = 0; mt < 4; ++mt)
#pragma unroll
                for (int nt = 0; nt < 2; ++nt) {
                    const float4 o = *(const float4*)&red[kh][lane][(mt * 2 + nt) * 4];
                    acc[mt][nt].x += o.x; acc[mt][nt].y += o.y;
                    acc[mt][nt].z += o.z; acc[mt][nt].w += o.w;
                }
        }
        __syncthreads();
        if (kh == 1) {
#pragma unroll
            for (int mt = 0; mt < 4; ++mt)
#pragma unroll
                for (int nt = 0; nt < 2; ++nt)
                    *(float4*)&red[0][lane][(mt * 2 + nt) * 4] = *(float4*)&acc[mt][nt];
        }
        __syncthreads();
        if (kh == 0) {
            const int prow = (lane >> 4) * 4;
#pragma unroll
            for (int nt = 0; nt < 2; ++nt) {
                const int oc = nt * 16 + l15;
                if (oc < 18) {
                    const float bs = bias[oc];
#pragma unroll
                    for (int mt = 0; mt < 4; ++mt) {
                        float4 r = *(float4*)&acc[mt][nt];
                        const float4 o = *(const float4*)&red[0][lane][(mt * 2 + nt) * 4];
                        r.x += o.x + bs; r.y += o.y + bs;
                        r.z += o.z + bs; r.w += o.w + bs;
                        *(float4*)(ooff + ((size_t)b * 18 + oc) * HW + px0 + mt * 16 + prow) = r;
                        *(float4*)&offsL[oc][mt * 16 + prow] = r;
                    }
                }
            }
        }
        __syncthreads();     // offsL visible; red region dead
    }

    // ===================== phase B: bilinear params ========================
#pragma unroll
    for (int u = 0; u < 2; ++u) {
        const int s = t + u * 512;
        if (s < DM * 9) {
            const int p = s / 9, k = s - 9 * p;
            const int pix = px0 + p;
            const int hh = pix >> sh;
            const int ww = pix & (W - 1);
            const float dy = offsL[2 * k    ][p];
            const float dx = offsL[2 * k + 1][p];
            const float sy = (float)(hh + k / 3 - 1) + dy;
            const float sx = (float)(ww + k % 3 - 1) + dx;
            const float y0f = floorf(sy), x0f = floorf(sx);
            const float ly = sy - y0f, lx = sx - x0f;
            const int y0 = (int)y0f, x0 = (int)x0f;
#pragma unroll
            for (int j = 0; j < 4; ++j) {
                const int yy = y0 + (j >> 1);
                const int xx = x0 + (j & 1);
                const bool ok = ((unsigned)yy < (unsigned)H) && ((unsigned)xx < (unsigned)W);
                sidxS[p][k][j] = (short)(min(max(yy, 0), H - 1) * W + min(max(xx, 0), W - 1));
                const float wj = ((j >> 1) ? ly : 1.f - ly) * ((j & 1) ? lx : 1.f - lx);
                swtH[p][k][j] = (_Float16)(ok ? wj : 0.f);
            }
        }
    }
    __syncthreads();

    // ===================== phase C: deform GEMM (r5 loop) ==================
    const int ocb = wv * 32;
    const bool live4 = (t < 256);         // 2304 - 4*512 = 256 fifth-units

    const int g0  = t >> 2;
    const int cgE = (t & 3) * 8;
    int uso[5];
#pragma unroll
    for (int q = 0; q < 5; ++q) {
        const int g  = g0 + q * 128;
        const int px = g / 9, tap = g - 9 * px;
        uso[q] = px * SSTR + tap * 32 + (t & 3) * 8;
    }

    const ushort_t* wrow0 = wgd + (size_t)(ocb      + l15) * K_TOT + cg8;
    const ushort_t* wrow1 = wgd + (size_t)(ocb + 16 + l15) * K_TOT + cg8;
    ushort_t* smpb = &smp[0][0];
    const sh4* sidxF = (const sh4*)(uni + 37888);
    const h4*  swtF  = (const h4*) (uni + 42496);

    f32x4 acc[4][2] = {};

    for (int cc = 0; cc < NCHK; ++cc) {
        const int cb = cc * 32 + cgE;
        const size_t kg0 = (size_t)cc * KCH;

        // ---- gather phase: depth-2 rolling pipeline (cA/cB slots) ---------
        bf16x8 cA[4], cB[4];
        float4 wA, wB;
        bf16x8 bq[2][2];
        {
            const sh4 iv = sidxF[g0]; const h4 wvv = swtF[g0];
            const int4 id = {iv.x, iv.y, iv.z, iv.w};
            wA = (float4){(float)wvv.x, (float)wvv.y, (float)wvv.z, (float)wvv.w};
            dcn_load4(cA, xtb, id, cb);
        }
        {
            const sh4 iv = sidxF[g0 + 128]; const h4 wvv = swtF[g0 + 128];
            const int4 id = {iv.x, iv.y, iv.z, iv.w};
            wB = (float4){(float)wvv.x, (float)wvv.y, (float)wvv.z, (float)wvv.w};
            dcn_load4(cB, xtb, id, cb);
        }
        bq[0][0] = *(const bf16x8*)&wrow0[kg0];
        bq[0][1] = *(const bf16x8*)&wrow1[kg0];

        dcn_proc2(smpb, uso[0], cA, wA);
        {
            const sh4 iv = sidxF[g0 + 256]; const h4 wvv = swtF[g0 + 256];
            const int4 id = {iv.x, iv.y, iv.z, iv.w};
            wA = (float4){(float)wvv.x, (float)wvv.y, (float)wvv.z, (float)wvv.w};
            dcn_load4(cA, xtb, id, cb);
        }
        dcn_proc2(smpb, uso[1], cB, wB);
        {
            const sh4 iv = sidxF[g0 + 384]; const h4 wvv = swtF[g0 + 384];
            const int4 id = {iv.x, iv.y, iv.z, iv.w};
            wB = (float4){(float)wvv.x, (float)wvv.y, (float)wvv.z, (float)wvv.w};
            dcn_load4(cB, xtb, id, cb);
        }
        dcn_proc2(smpb, uso[2], cA, wA);
        if (live4) {
            const sh4 iv = sidxF[g0 + 512]; const h4 wvv = swtF[g0 + 512];
            const int4 id = {iv.x, iv.y, iv.z, iv.w};
            wA = (float4){(float)wvv.x, (float)wvv.y, (float)wvv.z, (float)wvv.w};
            dcn_load4(cA, xtb, id, cb);
        }
        dcn_proc2(smpb, uso[3], cB, wB);
        if (live4) dcn_proc2(smpb, uso[4], cA, wA);

        // ---- barrier A: smp writes visible (lgkm only, vmem in flight) ----
        asm volatile("s_waitcnt lgkmcnt(0)" ::: "memory");
        __builtin_amdgcn_sched_barrier(0);
        __builtin_amdgcn_s_barrier();
        __builtin_amdgcn_sched_barrier(0);

        // ---- MFMA phase: rolling 2-deep B register buffer -----------------
        __builtin_amdgcn_s_setprio(1);
#pragma unroll
        for (int ks = 0; ks < 9; ++ks) {
            if (ks < 8) {
                bq[(ks + 1) & 1][0] = *(const bf16x8*)&wrow0[kg0 + (size_t)(ks + 1) * 32];
                bq[(ks + 1) & 1][1] = *(const bf16x8*)&wrow1[kg0 + (size_t)(ks + 1) * 32];
            }
            bf16x8 a[4];
#pragma unroll
            for (int mt = 0; mt < 4; ++mt)
                a[mt] = *(const bf16x8*)&smp[mt * 16 + l15][ks * 32 + cg8];
#pragma unroll
            for (int mt = 0; mt < 4; ++mt) {
                acc[mt][0] = __builtin_amdgcn_mfma_f32_16x16x32_bf16(a[mt], bq[ks & 1][0], acc[mt][0], 0, 0, 0);
                acc[mt][1] = __builtin_amdgcn_mfma_f32_16x16x32_bf16(a[mt], bq[ks & 1][1], acc[mt][1], 0, 0, 0);
            }
        }
        __builtin_amdgcn_s_setprio(0);

        // ---- barrier B: all smp reads consumed before next chunk's writes -
        if (cc < NCHK - 1) {
            __builtin_amdgcn_sched_barrier(0);
            __builtin_amdgcn_s_barrier();
            __builtin_amdgcn_sched_barrier(0);
        }
    }

    // ---- epilogue ---------------------------------------------------------
    const int prow = (lane >> 4) * 4;
#pragma unroll
    for (int mt = 0; mt < 4; ++mt) {
#pragma unroll
        for (int nt = 0; nt < 2; ++nt) {
            const int oc = ocb + nt * 16 + l15;
            float* op = out + ((size_t)b * OC + oc) * HW + px0 + mt * 16 + prow;
            *(float4*)op = *(float4*)&acc[mt][nt];
        }
    }
}

// ---------------------------------------------------------------------------
// Launcher. Inputs: kernel, search, Toffset_w, Toffset_b, Tdeform_w,
//                   Soffset_w, Soffset_b, Sdeform_w
// Outputs: kernel_out[16,256,16,16], search_out[16,256,32,32],
//          kernel_offset[16,18,16,16], search_offset[16,18,32,32]
// d_ws: 13.15 MB (bf16 weights 2.66 MB + HWC inputs 10.49 MB + 512 B zero
// row appended after xt_s for OOB taps).
// ---------------------------------------------------------------------------
extern "C" void kernel_launch(void* const* d_in, const int* in_sizes, int n_in,
                              void* d_out, int out_size, void* d_ws, size_t ws_size,
                              hipStream_t stream) {
    const float* kin = (const float*)d_in[0];
    const float* sin_ = (const float*)d_in[1];
    const float* tow = (const float*)d_in[2];
    const float* tob = (const float*)d_in[3];
    const float* tdw = (const float*)d_in[4];
    const float* sow = (const float*)d_in[5];
    const float* sob = (const float*)d_in[6];
    const float* sdw = (const float*)d_in[7];

    float* out = (float*)d_out;
    float* out_k  = out;                                      // 16*256*16*16
    float* out_s  = out_k + (size_t)16 * 256 * 16 * 16;       // 16*256*32*32
    float* out_ko = out_s + (size_t)16 * 256 * 32 * 32;       // 16*18*16*16
    float* out_so = out_ko + (size_t)16 * 18 * 16 * 16;       // 16*18*32*32

    ushort_t* wk_d = (ushort_t*)d_ws;                 // [256][2304] tap-major
    ushort_t* ws_d = wk_d + N_DW;
    ushort_t* wk_o = ws_d + N_DW;                     // [32][2304] tap-major
    ushort_t* ws_o = wk_o + N_OW;
    ushort_t* xt_k = ws_o + N_OW;                     // [16][256][256] HWC bf16
    ushort_t* xt_s = xt_k + XT_K_ELEMS;               // [16][1024][256]
    // zero row (256 elems) lives at xt_s + XT_S_ELEMS; prep_k writes it.

    prep_k<<<dim3(CVT_BLOCKS + 320), 512, 0, stream>>>(
        tdw, sdw, tow, sow, kin, sin_,
        wk_d, ws_d, wk_o, ws_o, xt_k, xt_s);

    deform_gemm_k<<<dim3(320), 512, 0, stream>>>(
        xt_k, wk_o, tob, out_ko, wk_d, out_k,
        xt_s, ws_o, sob, out_so, ws_d, out_s);
}